// Round 17
// baseline (336.247 us; speedup 1.0000x reference)
//
#include <hip/hip_runtime.h>

#define NN 100000
#define EE 1600000
#define GG 64
#define EPSF 1e-5f
#define NB 391   // ceil(NN/256)
#define CAP 48   // CSR slots per node (Poisson(16); P(any overflow) ~ 6e-6)
#define PB 1024  // pool stage-1 blocks
#define EG 6250  // edge chunks (EE/256), exact
#define B1 6250  // pass1 bucket size (NN/16 nodes)
#define Q1CAP 2048   // per (bucket16, sub64) queue cap (mean 1563, +12 sigma)
#define SBN 196      // pass3 sub-bucket nodes (32 per bucket: 32*196=6272>=6250)
#define Q2CAP 512    // per (fb512, sub2 16) queue cap (mean 196, +15 sigma)
#define ZWORDS 151616  // zero region: pacc(16384)+qc1(65536)+qc2(524288)+done(256) bytes /4
#define ZB 593         // ceil(ZWORDS/256)

typedef short short8 __attribute__((ext_vector_type(8)));
typedef float f32x4 __attribute__((ext_vector_type(4)));

// ---------------- bf16 helpers ----------------

__device__ __forceinline__ unsigned pack_bf16(float a, float b) {
  unsigned ua = __float_as_uint(a);
  unsigned ub = __float_as_uint(b);
  ua = (ua + 0x7fffu + ((ua >> 16) & 1u)) >> 16;           // RNE, low half
  ub = (ub + 0x7fffu + ((ub >> 16) & 1u)) & 0xffff0000u;   // RNE, high half
  return ua | ub;
}
__device__ __forceinline__ unsigned short bf16_1(float a) {
  unsigned u = __float_as_uint(a);
  return (unsigned short)((u + 0x7fffu + ((u >> 16) & 1u)) >> 16);
}
__device__ __forceinline__ float blo(unsigned u) { return __uint_as_float(u << 16); }
__device__ __forceinline__ float bhi(unsigned u) { return __uint_as_float(u & 0xffff0000u); }

__device__ __forceinline__ void acc_u4(float* a, uint4 u) {
  a[0] += blo(u.x); a[1] += bhi(u.x);
  a[2] += blo(u.y); a[3] += bhi(u.y);
  a[4] += blo(u.z); a[5] += bhi(u.z);
  a[6] += blo(u.w); a[7] += bhi(u.w);
}

// 32-bit voffset gather (SADDR + unsigned byte offset)
__device__ __forceinline__ uint4 ldg_off(const void* base, unsigned off) {
  return *(const uint4*)((const char*)base + off);
}

// ---------------- CSR build: 3-pass LDS-assembled ----------------
// Invariant (R11/R12/R15): scattered 4B global stores cost ~64MB WRITE at
// ~0.95TB/s regardless of locality strategy. Fix: NEVER scatter to global.
// P1/P2 bin edges via LDS lists flushed as contiguous appends; P3 assembles
// each 196-node CSR window in LDS and writes dense+coalesced. P3 also fuses
// premul (xs = x * rsqrt(deg), bf16) since it holds the degrees in LDS.
// pack = (src << 13) | (dst - bucket*B1).

__global__ __launch_bounds__(256) void p1_k(const int* __restrict__ src,
                                            const int* __restrict__ dst,
                                            int* __restrict__ qc1,
                                            unsigned* __restrict__ q1) {
  __shared__ unsigned lst[16][48];
  __shared__ int lcnt[16];
  __shared__ int lbase[16];
  int tid = threadIdx.x;
  if (tid < 16) lcnt[tid] = 0;
  __syncthreads();
  int e = blockIdx.x * 256 + tid;  // EE = EG*256 exactly
  int d = __builtin_nontemporal_load(&dst[e]);
  int s = __builtin_nontemporal_load(&src[e]);
  int b = d / B1;                  // 0..15
  unsigned pack = ((unsigned)s << 13) | (unsigned)(d - b * B1);
  int sub = blockIdx.x & 63;
  int pos = atomicAdd(&lcnt[b], 1);
  if (pos < 48) {
    lst[b][pos] = pack;
  } else {  // rare overflow: direct append
    int gp = atomicAdd(&qc1[(b * 64 + sub) * 16], 1);
    if (gp < Q1CAP) q1[(b * 64 + sub) * Q1CAP + gp] = pack;
  }
  __syncthreads();
  if (tid < 16) lbase[tid] = atomicAdd(&qc1[(tid * 64 + sub) * 16], min(lcnt[tid], 48));
  __syncthreads();
  for (int i = tid; i < 16 * 48; i += 256) {
    int l = i / 48, k = i % 48;
    if (k < min(lcnt[l], 48)) {
      int p = lbase[l] + k;
      if (p < Q1CAP) q1[(l * 64 + sub) * Q1CAP + p] = lst[l][k];
    }
  }
}

__global__ __launch_bounds__(256) void p2_k(const unsigned* __restrict__ q1,
                                            const int* __restrict__ qc1,
                                            int* __restrict__ qc2,
                                            unsigned* __restrict__ q2) {
  __shared__ unsigned lst[32][64];
  __shared__ int lcnt[32];
  __shared__ int lbase[32];
  int tid = threadIdx.x;
  if (tid < 32) lcnt[tid] = 0;
  __syncthreads();
  int t = blockIdx.x;
  int b = t >> 8;                 // bucket 0..15
  int rem = t & 255;
  int sub64 = rem >> 2, chunk = rem & 3;   // 64 subs x 4 chunks of 512
  int sub2 = t & 15;
  int qi = b * 64 + sub64;
  int len = min(qc1[qi * 16], Q1CAP);
#pragma unroll
  for (int h = 0; h < 2; ++h) {
    int e = chunk * 512 + h * 256 + tid;
    if (e < len) {
      unsigned p = q1[qi * Q1CAP + e];
      int doff = (int)(p & 8191u);
      int sb = doff / SBN;        // 0..31
      int pos = atomicAdd(&lcnt[sb], 1);
      if (pos < 64) {
        lst[sb][pos] = p;
      } else {  // rare overflow: direct append
        int fb = b * 32 + sb;
        int gp = atomicAdd(&qc2[(fb * 16 + sub2) * 16], 1);
        if (gp < Q2CAP) q2[(size_t)(fb * 16 + sub2) * Q2CAP + gp] = p;
      }
    }
  }
  __syncthreads();
  if (tid < 32) {
    int fb = b * 32 + tid;
    lbase[tid] = atomicAdd(&qc2[(fb * 16 + sub2) * 16], min(lcnt[tid], 64));
  }
  __syncthreads();
  for (int i = tid; i < 32 * 64; i += 256) {
    int l = i >> 6, k = i & 63;
    if (k < min(lcnt[l], 64)) {
      int p = lbase[l] + k;
      int fb = b * 32 + l;
      if (p < Q2CAP) q2[(size_t)(fb * 16 + sub2) * Q2CAP + p] = lst[l][k];
    }
  }
}

// P3: assemble 196-node CSR window in LDS, write dense+coalesced; fused premul.
__global__ __launch_bounds__(256) void p3_k(const unsigned* __restrict__ q2,
                                            const int* __restrict__ qc2,
                                            const float* __restrict__ x,
                                            int* __restrict__ cursor,
                                            int* __restrict__ csr,
                                            unsigned* __restrict__ xs) {
  __shared__ int lcsr[SBN * CAP];   // 37632 B
  __shared__ int lcnt[SBN];
  int tid = threadIdx.x;
  int fb = blockIdx.x;              // 0..511
  int b = fb >> 5, sb = fb & 31;
  int node_lo = b * B1 + sb * SBN;
  int node_hi = min(node_lo + SBN, (b + 1) * B1);
  int nn = node_hi - node_lo;       // 196 or 174 (sb=31)
  if (nn <= 0) return;
  for (int i = tid; i < SBN; i += 256) lcnt[i] = 0;
  __syncthreads();
  int base_off = sb * SBN;
#pragma unroll 1
  for (int s2 = 0; s2 < 16; ++s2) {
    int qi = fb * 16 + s2;
    int len = min(qc2[qi * 16], Q2CAP);
    for (int i = tid; i < len; i += 256) {
      unsigned p = q2[(size_t)qi * Q2CAP + i];
      int local = (int)(p & 8191u) - base_off;   // 0..nn-1 by construction
      int s = (int)(p >> 13);
      int pos = atomicAdd(&lcnt[local], 1);
      if (pos < CAP) lcsr[local * CAP + pos] = s;
    }
  }
  __syncthreads();
  for (int i = tid; i < nn; i += 256) cursor[node_lo + i] = lcnt[i];
  // dense contiguous CSR write: nn*CAP ints = nn*12 uint4, 16B aligned
  uint4* gout = (uint4*)&csr[(size_t)node_lo * CAP];
  const uint4* lin = (const uint4*)lcsr;
  for (int i = tid; i < nn * (CAP / 4); i += 256) gout[i] = lin[i];
  // fused premul: xs[node] = x[node] * rsqrt(deg+1), packed bf16
  for (int i = tid; i < nn * 32; i += 256) {
    int ln = i >> 5, j = i & 31;
    int node = node_lo + ln;
    float dsc = rsqrtf((float)lcnt[ln] + 1.0f);
    float2 v = ((const float2*)x)[(size_t)node * 32 + j];
    xs[(size_t)node * 32 + j] = pack_bf16(v.x * dsc, v.y * dsc);
  }
}

// ---------------- merged setup: weights, BN fold, boundaries, zeroing ----------------

__global__ __launch_bounds__(256) void setup_k(
    const float* __restrict__ W0, const float* __restrict__ W1,
    const float* __restrict__ W2, unsigned short* __restrict__ wt0,
    unsigned short* __restrict__ wt1, unsigned short* __restrict__ wt2,
    const float* __restrict__ b0, const float* __restrict__ g0,
    const float* __restrict__ be0, const float* __restrict__ m0,
    const float* __restrict__ v0, const float* __restrict__ b1,
    const float* __restrict__ g1, const float* __restrict__ be1,
    const float* __restrict__ m1, const float* __restrict__ v1,
    float* __restrict__ s0, float* __restrict__ h0,
    float* __restrict__ s1, float* __restrict__ h1,
    const int* __restrict__ batch, int* __restrict__ start,
    int* __restrict__ zbase) {
  int bid = blockIdx.x;
  if (bid < 128) {                       // weight prep
    int i = bid * 256 + threadIdx.x;
    if (i < 8192) {                      // Wt0 [128][64]
      int d = i >> 6, k = i & 63;
      wt0[d * 64 + k] = bf16_1(W0[k * 128 + d]);
    } else if (i < 24576) {              // Wt1 [128][128]
      int j = i - 8192;
      int d = j >> 7, k = j & 127;
      wt1[d * 128 + k] = bf16_1(W1[k * 128 + d]);
    } else if (i < 32768) {              // Wt2 [64][128]
      int j = i - 24576;
      int d = j >> 7, k = j & 127;
      wt2[d * 128 + k] = bf16_1(W2[k * 64 + d]);
    }
  } else if (bid == 128) {               // BN fold
    int i = threadIdx.x;
    if (i < 128) {
      float s = g0[i] * rsqrtf(v0[i] + EPSF);
      s0[i] = s;
      h0[i] = be0[i] + (b0[i] - m0[i]) * s;
    } else {
      int j = i - 128;
      float s = g1[j] * rsqrtf(v1[j] + EPSF);
      s1[j] = s;
      h1[j] = be1[j] + (b1[j] - m1[j]) * s;
    }
  } else if (bid < 129 + NB) {           // graph boundaries
    int i = (bid - 129) * 256 + threadIdx.x;
    if (i >= NN) return;
    int b = batch[i];
    if (i == 0) {
      for (int g = 0; g <= b; ++g) start[g] = 0;
    } else {
      int p = batch[i - 1];
      for (int g = p + 1; g <= b; ++g) start[g] = i;
    }
    if (i == NN - 1) {
      for (int g = b + 1; g <= GG; ++g) start[g] = NN;
    }
  } else {                               // zero pacc/qc1/qc2/done
    int i = (bid - 129 - NB) * 256 + threadIdx.x;
    if (i < ZWORDS) zbase[i] = 0;
  }
}

// ---------------- Aggregation (bf16 in, fp32 accumulate, bf16 out) ----------------
// out[n] = dinv[n] * ( sum_{s} xp[s] + xp[n] ), xp premultiplied by dinv[s].
// One coalesced index load per node; self appended as pseudo-neighbor.
// Loops have WAVE-UNIFORM trip counts; __shfl always full-wave. Only gathers
// predicated (R8 lesson: ds_bpermute from EXEC-inactive lane is undefined).

// 64-ch: row = 128B = 8 lanes x uint4; 16 edges per iteration (2 in flight).
__global__ __launch_bounds__(256) void aggp64_k(const unsigned* __restrict__ xp,
                                                const int* __restrict__ counts,
                                                const int* __restrict__ csr,
                                                uint4* __restrict__ out4) {
  int node = blockIdx.x * 4 + (threadIdx.x >> 6);
  if (node >= NN) return;
  int lane = threadIdx.x & 63;
  int g = lane >> 3, sl = lane & 7;
  int raw = counts[node];
  float di = rsqrtf((float)raw + 1.0f);
  int cnt = min(raw, CAP);
  int idx = (lane < cnt) ? csr[node * CAP + lane] : node;  // self at pos cnt
  cnt += 1;
  unsigned slb = (unsigned)(sl << 4);
  float a[8] = {0.f, 0.f, 0.f, 0.f, 0.f, 0.f, 0.f, 0.f};
  for (int base = 0; base < cnt; base += 16) {   // uniform trip count
    int j0 = base + g, j1 = base + g + 8;
    int s0 = __shfl(idx, j0, 64);                // j <= 63 always
    int s1 = __shfl(idx, j1, 64);
    if (j0 < cnt) acc_u4(a, ldg_off(xp, (unsigned)s0 * 128u + slb));
    if (j1 < cnt) acc_u4(a, ldg_off(xp, (unsigned)s1 * 128u + slb));
  }
#pragma unroll
  for (int i = 0; i < 8; ++i) {
    a[i] += __shfl_xor(a[i], 8, 64);
    a[i] += __shfl_xor(a[i], 16, 64);
    a[i] += __shfl_xor(a[i], 32, 64);
  }
  if (g == 0) {
    uint4 o;
    o.x = pack_bf16(a[0] * di, a[1] * di);
    o.y = pack_bf16(a[2] * di, a[3] * di);
    o.z = pack_bf16(a[4] * di, a[5] * di);
    o.w = pack_bf16(a[6] * di, a[7] * di);
    out4[(size_t)node * 8 + sl] = o;
  }
}

// 128-ch: row = 256B = 16 lanes x uint4; 16 edges per iteration (4 in flight).
__global__ __launch_bounds__(256) void aggp128_k(const unsigned* __restrict__ xp,
                                                 const int* __restrict__ counts,
                                                 const int* __restrict__ csr,
                                                 uint4* __restrict__ out4) {
  int node = blockIdx.x * 4 + (threadIdx.x >> 6);
  if (node >= NN) return;
  int lane = threadIdx.x & 63;
  int q = lane >> 4, sl = lane & 15;
  int raw = counts[node];
  float di = rsqrtf((float)raw + 1.0f);
  int cnt = min(raw, CAP);
  int idx = (lane < cnt) ? csr[node * CAP + lane] : node;  // self at pos cnt
  cnt += 1;
  unsigned slb = (unsigned)(sl << 4);
  float a[8] = {0.f, 0.f, 0.f, 0.f, 0.f, 0.f, 0.f, 0.f};
  for (int base = 0; base < cnt; base += 16) {   // uniform trip count
    int j0 = base + q, j1 = base + q + 4, j2 = base + q + 8, j3 = base + q + 12;
    int s0 = __shfl(idx, j0, 64);                // j <= 63 always
    int s1 = __shfl(idx, j1, 64);
    int s2 = __shfl(idx, j2, 64);
    int s3 = __shfl(idx, j3, 64);
    if (j0 < cnt) acc_u4(a, ldg_off(xp, (unsigned)s0 * 256u + slb));
    if (j1 < cnt) acc_u4(a, ldg_off(xp, (unsigned)s1 * 256u + slb));
    if (j2 < cnt) acc_u4(a, ldg_off(xp, (unsigned)s2 * 256u + slb));
    if (j3 < cnt) acc_u4(a, ldg_off(xp, (unsigned)s3 * 256u + slb));
  }
#pragma unroll
  for (int i = 0; i < 8; ++i) {
    a[i] += __shfl_xor(a[i], 16, 64);
    a[i] += __shfl_xor(a[i], 32, 64);
  }
  if (q == 0) {
    uint4 o;
    o.x = pack_bf16(a[0] * di, a[1] * di);
    o.y = pack_bf16(a[2] * di, a[3] * di);
    o.z = pack_bf16(a[4] * di, a[5] * di);
    o.w = pack_bf16(a[6] * di, a[7] * di);
    out4[(size_t)node * 16 + sl] = o;
  }
}

// final agg + bias + LayerNorm (64-ch bf16 in, fp32 out), eighth-wave gather.
__global__ __launch_bounds__(256) void agg_ln_k(const unsigned* __restrict__ xp,
                                                const int* __restrict__ counts,
                                                const int* __restrict__ csr,
                                                const float* __restrict__ bias,
                                                const float* __restrict__ lng,
                                                const float* __restrict__ lnb,
                                                float* __restrict__ out) {
  int node = blockIdx.x * 4 + (threadIdx.x >> 6);
  if (node >= NN) return;
  int lane = threadIdx.x & 63;
  int g = lane >> 3, sl = lane & 7;
  int raw = counts[node];
  float di = rsqrtf((float)raw + 1.0f);
  int cnt = min(raw, CAP);
  int idx = (lane < cnt) ? csr[node * CAP + lane] : node;  // self at pos cnt
  cnt += 1;
  unsigned slb = (unsigned)(sl << 4);
  float a[8] = {0.f, 0.f, 0.f, 0.f, 0.f, 0.f, 0.f, 0.f};
  for (int base = 0; base < cnt; base += 16) {   // uniform trip count
    int j0 = base + g, j1 = base + g + 8;
    int s0 = __shfl(idx, j0, 64);                // j <= 63 always
    int s1 = __shfl(idx, j1, 64);
    if (j0 < cnt) acc_u4(a, ldg_off(xp, (unsigned)s0 * 128u + slb));
    if (j1 < cnt) acc_u4(a, ldg_off(xp, (unsigned)s1 * 128u + slb));
  }
#pragma unroll
  for (int i = 0; i < 8; ++i) {
    a[i] += __shfl_xor(a[i], 8, 64);
    a[i] += __shfl_xor(a[i], 16, 64);
    a[i] += __shfl_xor(a[i], 32, 64);
  }
  // all lanes now hold channels sl*8..sl*8+7
  float4 b0 = ((const float4*)bias)[sl * 2];
  float4 b1 = ((const float4*)bias)[sl * 2 + 1];
  float v[8];
  v[0] = a[0] * di + b0.x; v[1] = a[1] * di + b0.y;
  v[2] = a[2] * di + b0.z; v[3] = a[3] * di + b0.w;
  v[4] = a[4] * di + b1.x; v[5] = a[5] * di + b1.y;
  v[6] = a[6] * di + b1.z; v[7] = a[7] * di + b1.w;
  float s = ((v[0] + v[1]) + (v[2] + v[3])) + ((v[4] + v[5]) + (v[6] + v[7]));
#pragma unroll
  for (int off = 1; off < 8; off <<= 1) s += __shfl_xor(s, off, 64);
  float mu = s * (1.f / 64.f);
  float vs = 0.f;
#pragma unroll
  for (int i = 0; i < 8; ++i) {
    v[i] -= mu;
    vs += v[i] * v[i];
  }
#pragma unroll
  for (int off = 1; off < 8; off <<= 1) vs += __shfl_xor(vs, off, 64);
  float r = rsqrtf(vs * (1.f / 64.f) + EPSF);
  if (g == 0) {
    float4 g0 = ((const float4*)lng)[sl * 2];
    float4 g1 = ((const float4*)lng)[sl * 2 + 1];
    float4 e0 = ((const float4*)lnb)[sl * 2];
    float4 e1 = ((const float4*)lnb)[sl * 2 + 1];
    float4 o0, o1;
    o0.x = v[0] * r * g0.x + e0.x; o0.y = v[1] * r * g0.y + e0.y;
    o0.z = v[2] * r * g0.z + e0.z; o0.w = v[3] * r * g0.w + e0.w;
    o1.x = v[4] * r * g1.x + e1.x; o1.y = v[5] * r * g1.y + e1.y;
    o1.z = v[6] * r * g1.z + e1.z; o1.w = v[7] * r * g1.w + e1.w;
    ((float4*)out)[(size_t)node * 16 + sl * 2] = o0;
    ((float4*)out)[(size_t)node * 16 + sl * 2 + 1] = o1;
  }
}

// ---------------- MFMA GEMM: C[N,D] = A[N,K] @ W[K,D], bf16 in/out ----------------

#define EPI_BNRELU 1
#define EPI_BNRELU_PREMUL 2
#define EPI_PREMUL 3

template <int K, int D, int EPI>
__global__ __launch_bounds__(256, 2) void gemm_mfma_k(
    const unsigned short* __restrict__ Abf,   // [N][K] bf16
    const unsigned short* __restrict__ Wt,    // [D][K] bf16 (pre-transposed)
    const float* __restrict__ scale,          // [D]
    const float* __restrict__ shift,          // [D]
    const int* __restrict__ counts,
    unsigned short* __restrict__ C) {         // [N][D] bf16
  constexpr int BM = 64;
  constexpr int LK = K + 8;                   // +16B pad: 2-way bank alias (free)
  constexpr int NT = D / 16;
  __shared__ unsigned short sA[BM * LK];
  __shared__ unsigned short sW[D * LK];
  int tid = threadIdx.x;
  int row0 = blockIdx.x * BM;
  for (int i = tid; i < BM * K / 8; i += 256) {
    int r = i / (K / 8), c8 = i % (K / 8);
    int gr = row0 + r;
    short8 v = {};
    if (gr < NN) v = *(const short8*)&Abf[(size_t)gr * K + c8 * 8];
    *(short8*)&sA[r * LK + c8 * 8] = v;
  }
  for (int i = tid; i < D * K / 8; i += 256) {
    int d = i / (K / 8), c8 = i % (K / 8);
    *(short8*)&sW[d * LK + c8 * 8] = *(const short8*)&Wt[d * K + c8 * 8];
  }
  __syncthreads();
  int wid = tid >> 6, lane = tid & 63;
  int lr = lane & 15, kg = lane >> 4;
  f32x4 acc[NT];
#pragma unroll
  for (int t = 0; t < NT; ++t) acc[t] = (f32x4){0.f, 0.f, 0.f, 0.f};
  const unsigned short* pa = &sA[(wid * 16 + lr) * LK + kg * 8];
#pragma unroll
  for (int kk = 0; kk < K / 32; ++kk) {
    short8 a = *(const short8*)(pa + kk * 32);
#pragma unroll
    for (int t = 0; t < NT; ++t) {
      short8 b = *(const short8*)&sW[(t * 16 + lr) * LK + kk * 32 + kg * 8];
      acc[t] = __builtin_amdgcn_mfma_f32_16x16x32_bf16(a, b, acc[t], 0, 0, 0);
    }
  }
  int rbase = row0 + wid * 16 + kg * 4;
  float dv[4];
  if (EPI != EPI_BNRELU) {
#pragma unroll
    for (int j = 0; j < 4; ++j)
      dv[j] = (rbase + j < NN) ? rsqrtf((float)counts[rbase + j] + 1.0f) : 0.f;
  }
#pragma unroll
  for (int t = 0; t < NT; ++t) {
    int col = t * 16 + lr;
    float sc = 1.f, sh = 0.f;
    if (EPI != EPI_PREMUL) { sc = scale[col]; sh = shift[col]; }
#pragma unroll
    for (int j = 0; j < 4; ++j) {
      int r = rbase + j;
      if (r >= NN) continue;
      float v = acc[t][j];
      if (EPI != EPI_PREMUL) v = fmaxf(v * sc + sh, 0.f);
      if (EPI != EPI_BNRELU) v *= dv[j];
      C[(size_t)r * D + col] = bf16_1(v);
    }
  }
}

// ---------------- Pooling (single dispatch; last-block finalize) ----------------

__global__ __launch_bounds__(256) void pool_k(const float* __restrict__ ne,
                                              const int* __restrict__ batch,
                                              const int* __restrict__ start,
                                              float* __restrict__ acc,
                                              float* __restrict__ ge,
                                              int* __restrict__ done) {
  const int CHUNK = (NN + PB - 1) / PB;  // 98
  int i0 = blockIdx.x * CHUNK;
  int i1 = min(i0 + CHUNK, NN);
  if (i0 < NN) {
    int c = threadIdx.x & 63;
    int part = threadIdx.x >> 6;  // 0..3
    int cur = -1;
    float a = 0.f;
    for (int i = i0 + part; i < i1; i += 4) {
      int b = batch[i];  // wave-uniform
      if (b != cur) {
        if (cur >= 0) atomicAdd(&acc[cur * 64 + c], a);
        cur = b;
        a = 0.f;
      }
      a += ne[(size_t)i * 64 + c];
    }
    if (cur >= 0) atomicAdd(&acc[cur * 64 + c], a);
  }
  // last-block finalize (all PB blocks take a ticket)
  __shared__ int ticket;
  __threadfence();
  if (threadIdx.x == 0) ticket = atomicAdd(done, 1);
  __syncthreads();
  if (ticket == PB - 1) {
    __threadfence();
    for (int i = threadIdx.x; i < GG * 64; i += 256) {
      int g = i >> 6;
      float cnt = (float)(start[g + 1] - start[g]);
      ge[i] = acc[i] / fmaxf(cnt, 1.f);
    }
  }
}

// ---------------- launch ----------------

extern "C" void kernel_launch(void* const* d_in, const int* in_sizes, int n_in,
                              void* d_out, int out_size, void* d_ws, size_t ws_size,
                              hipStream_t stream) {
  const float* x = (const float*)d_in[0];
  const int* ei = (const int*)d_in[1];
  const int* srcv = ei;
  const int* dstv = ei + EE;
  const int* batch = (const int*)d_in[2];
  const float* W0 = (const float*)d_in[3];
  const float* b0 = (const float*)d_in[4];
  const float* W1 = (const float*)d_in[5];
  const float* b1 = (const float*)d_in[6];
  const float* W2 = (const float*)d_in[7];
  const float* b2 = (const float*)d_in[8];
  const float* bn0g = (const float*)d_in[9];
  const float* bn0b = (const float*)d_in[10];
  const float* bn0m = (const float*)d_in[11];
  const float* bn0v = (const float*)d_in[12];
  const float* bn1g = (const float*)d_in[13];
  const float* bn1b = (const float*)d_in[14];
  const float* bn1m = (const float*)d_in[15];
  const float* bn1v = (const float*)d_in[16];
  const float* lng = (const float*)d_in[17];
  const float* lnb = (const float*)d_in[18];

  float* out_nodes = (float*)d_out;
  float* out_graph = out_nodes + (size_t)NN * 64;

  char* ws = (char*)d_ws;
  size_t off = 0;
  auto carve = [&](size_t bytes) {
    void* p = ws + off;
    off = (off + bytes + 255) & ~(size_t)255;
    return p;
  };
  int* cursor = (int*)carve((size_t)NN * 4);              // raw degree counts
  float* pacc = (float*)carve((size_t)GG * 64 * 4);       // 16384 } zeroed by
  int* qc1 = (int*)carve(16 * 64 * 16 * 4);               // 65536 } setup_k
  int* qc2 = (int*)carve(512 * 16 * 16 * 4);              // 524288} (ZWORDS
  int* done = (int*)carve(256);                           // 256   }  words)
  int* gstart = (int*)carve((size_t)(GG + 1) * 4);
  unsigned short* wt0 = (unsigned short*)carve(8192 * 2);
  unsigned short* wt1 = (unsigned short*)carve(16384 * 2);
  unsigned short* wt2 = (unsigned short*)carve(8192 * 2);
  float* s0 = (float*)carve(128 * 4);
  float* h0 = (float*)carve(128 * 4);
  float* s1 = (float*)carve(128 * 4);
  float* h1 = (float*)carve(128 * 4);
  int* csr = (int*)carve((size_t)NN * CAP * 4);           // 19.2 MB
  char* bufA = (char*)carve((size_t)NN * 128 * 4);        // 51.2 MB
  char* bufB = (char*)carve((size_t)NN * 128 * 4);        // 51.2 MB

  // buffer life plan (aliases; each region dead before its successor writes):
  unsigned* q1 = (unsigned*)bufB;            // 8.4 MB,  dead after p2
  unsigned* q2 = (unsigned*)bufA;            // 16.8 MB, dead after p3
  unsigned* xs = (unsigned*)(bufA + (size_t)32 * 1024 * 1024);  // 12.8 MB, by p3
  void* a0 = bufB;                           // aggp64 out (q1 dead)
  void* h0p = bufA;                          // gemm0 out (q2 dead; xs@32MB clear)
  void* a1 = bufB;                           // aggp128 out (a0 dead)
  void* h1b = bufA;                          // gemm1 out (h0p dead)
  void* xw2p = bufB;                         // gemm2 out (a1 dead)

  setup_k<<<129 + NB + ZB, 256, 0, stream>>>(W0, W1, W2, wt0, wt1, wt2,
                                             b0, bn0g, bn0b, bn0m, bn0v,
                                             b1, bn1g, bn1b, bn1m, bn1v,
                                             s0, h0, s1, h1, batch, gstart,
                                             (int*)pacc);
  // 3-pass LDS-assembled CSR build (no scattered global stores) + fused premul
  p1_k<<<EG, 256, 0, stream>>>(srcv, dstv, qc1, q1);
  p2_k<<<16 * 256, 256, 0, stream>>>(q1, qc1, qc2, q2);
  p3_k<<<512, 256, 0, stream>>>(q2, qc2, x, cursor, csr, xs);

  int agrid = (NN + 3) / 4;    // 25000
  int mgrid = (NN + 63) / 64;  // 1563

  // a0 = agg(xs) (bf16, 64ch)
  aggp64_k<<<agrid, 256, 0, stream>>>(xs, cursor, csr, (uint4*)a0);
  // h0p = relu(bn(a0@W0)) * dinv (bf16, 128ch)
  gemm_mfma_k<64, 128, EPI_BNRELU_PREMUL><<<mgrid, 256, 0, stream>>>(
      (const unsigned short*)a0, wt0, s0, h0, cursor, (unsigned short*)h0p);
  // a1 = agg(h0p) (bf16, 128ch)
  aggp128_k<<<agrid, 256, 0, stream>>>((const unsigned*)h0p, cursor, csr,
                                       (uint4*)a1);
  // h1 = relu(bn(a1@W1)) (bf16, 128ch)
  gemm_mfma_k<128, 128, EPI_BNRELU><<<mgrid, 256, 0, stream>>>(
      (const unsigned short*)a1, wt1, s1, h1, cursor, (unsigned short*)h1b);
  // xw2p = (h1@W2) * dinv (bf16, 64ch; bias b2 post-agg)
  gemm_mfma_k<128, 64, EPI_PREMUL><<<mgrid, 256, 0, stream>>>(
      (const unsigned short*)h1b, wt2, s1, h1, cursor, (unsigned short*)xw2p);
  // out_nodes = LN(agg(xw2p) + b2)
  agg_ln_k<<<agrid, 256, 0, stream>>>((const unsigned*)xw2p, cursor, csr, b2,
                                      lng, lnb, out_nodes);
  // single-dispatch graph mean pool (last block finalizes)
  pool_k<<<PB, 256, 0, stream>>>(out_nodes, batch, gstart, pacc, out_graph, done);
}

// Round 18
// 272.858 us; speedup vs baseline: 1.2323x; 1.2323x over previous
//
#include <hip/hip_runtime.h>

#define NN 100000
#define EE 1600000
#define GG 64
#define EPSF 1e-5f
#define NB 391   // ceil(NN/256)
#define CAP 48   // CSR slots per node (Poisson(16); P(any overflow) ~ 6e-6)
#define PB 1024  // pool stage-1 blocks
#define EG 6250  // edge chunks (EE/256), exact
#define B1 6250  // pass1 bucket size (NN/16 nodes)
#define Q1CAP 2048   // per (bucket16, sub64) queue cap (mean 1563, +12 sigma)
#define SBN 196      // pass3 sub-bucket nodes (32 per bucket: 32*196=6272>=6250)
#define Q2CAP 512    // per (fb512, sub2 16) queue cap (mean 196, +15 sigma)
#define ZWORDS 151616  // zero region: pacc(16384)+qc1(65536)+qc2(524288)+done(256) bytes /4
#define ZB 593         // ceil(ZWORDS/256)

typedef short short8 __attribute__((ext_vector_type(8)));
typedef float f32x4 __attribute__((ext_vector_type(4)));

// ---------------- bf16 helpers ----------------

__device__ __forceinline__ unsigned pack_bf16(float a, float b) {
  unsigned ua = __float_as_uint(a);
  unsigned ub = __float_as_uint(b);
  ua = (ua + 0x7fffu + ((ua >> 16) & 1u)) >> 16;           // RNE, low half
  ub = (ub + 0x7fffu + ((ub >> 16) & 1u)) & 0xffff0000u;   // RNE, high half
  return ua | ub;
}
__device__ __forceinline__ unsigned short bf16_1(float a) {
  unsigned u = __float_as_uint(a);
  return (unsigned short)((u + 0x7fffu + ((u >> 16) & 1u)) >> 16);
}
__device__ __forceinline__ float blo(unsigned u) { return __uint_as_float(u << 16); }
__device__ __forceinline__ float bhi(unsigned u) { return __uint_as_float(u & 0xffff0000u); }

__device__ __forceinline__ void acc_u4(float* a, uint4 u) {
  a[0] += blo(u.x); a[1] += bhi(u.x);
  a[2] += blo(u.y); a[3] += bhi(u.y);
  a[4] += blo(u.z); a[5] += bhi(u.z);
  a[6] += blo(u.w); a[7] += bhi(u.w);
}

// 32-bit voffset gather (SADDR + unsigned byte offset)
__device__ __forceinline__ uint4 ldg_off(const void* base, unsigned off) {
  return *(const uint4*)((const char*)base + off);
}

// ---------------- CSR build: 3-pass LDS-assembled ----------------
// Invariant (R11/R12/R15): scattered 4B global stores cost ~64MB WRITE at
// ~0.95TB/s regardless of locality strategy. Fix: NEVER scatter to global.
// P1/P2 bin edges via LDS lists flushed as contiguous appends; P3 assembles
// each 196-node CSR window in LDS and writes dense+coalesced. P3 also fuses
// premul (xs = x * rsqrt(deg), bf16) since it holds the degrees in LDS.
// pack = (src << 13) | (dst - bucket*B1).

__global__ __launch_bounds__(256) void p1_k(const int* __restrict__ src,
                                            const int* __restrict__ dst,
                                            int* __restrict__ qc1,
                                            unsigned* __restrict__ q1) {
  __shared__ unsigned lst[16][48];
  __shared__ int lcnt[16];
  __shared__ int lbase[16];
  int tid = threadIdx.x;
  if (tid < 16) lcnt[tid] = 0;
  __syncthreads();
  int e = blockIdx.x * 256 + tid;  // EE = EG*256 exactly
  int d = __builtin_nontemporal_load(&dst[e]);
  int s = __builtin_nontemporal_load(&src[e]);
  int b = d / B1;                  // 0..15
  unsigned pack = ((unsigned)s << 13) | (unsigned)(d - b * B1);
  int sub = blockIdx.x & 63;
  int pos = atomicAdd(&lcnt[b], 1);
  if (pos < 48) {
    lst[b][pos] = pack;
  } else {  // rare overflow: direct append
    int gp = atomicAdd(&qc1[(b * 64 + sub) * 16], 1);
    if (gp < Q1CAP) q1[(b * 64 + sub) * Q1CAP + gp] = pack;
  }
  __syncthreads();
  if (tid < 16) lbase[tid] = atomicAdd(&qc1[(tid * 64 + sub) * 16], min(lcnt[tid], 48));
  __syncthreads();
  for (int i = tid; i < 16 * 48; i += 256) {
    int l = i / 48, k = i % 48;
    if (k < min(lcnt[l], 48)) {
      int p = lbase[l] + k;
      if (p < Q1CAP) q1[(l * 64 + sub) * Q1CAP + p] = lst[l][k];
    }
  }
}

__global__ __launch_bounds__(256) void p2_k(const unsigned* __restrict__ q1,
                                            const int* __restrict__ qc1,
                                            int* __restrict__ qc2,
                                            unsigned* __restrict__ q2) {
  __shared__ unsigned lst[32][64];
  __shared__ int lcnt[32];
  __shared__ int lbase[32];
  int tid = threadIdx.x;
  if (tid < 32) lcnt[tid] = 0;
  __syncthreads();
  int t = blockIdx.x;
  int b = t >> 8;                 // bucket 0..15
  int rem = t & 255;
  int sub64 = rem >> 2, chunk = rem & 3;   // 64 subs x 4 chunks of 512
  int sub2 = t & 15;
  int qi = b * 64 + sub64;
  int len = min(qc1[qi * 16], Q1CAP);
#pragma unroll
  for (int h = 0; h < 2; ++h) {
    int e = chunk * 512 + h * 256 + tid;
    if (e < len) {
      unsigned p = q1[qi * Q1CAP + e];
      int doff = (int)(p & 8191u);
      int sb = doff / SBN;        // 0..31
      int pos = atomicAdd(&lcnt[sb], 1);
      if (pos < 64) {
        lst[sb][pos] = p;
      } else {  // rare overflow: direct append
        int fb = b * 32 + sb;
        int gp = atomicAdd(&qc2[(fb * 16 + sub2) * 16], 1);
        if (gp < Q2CAP) q2[(size_t)(fb * 16 + sub2) * Q2CAP + gp] = p;
      }
    }
  }
  __syncthreads();
  if (tid < 32) {
    int fb = b * 32 + tid;
    lbase[tid] = atomicAdd(&qc2[(fb * 16 + sub2) * 16], min(lcnt[tid], 64));
  }
  __syncthreads();
  for (int i = tid; i < 32 * 64; i += 256) {
    int l = i >> 6, k = i & 63;
    if (k < min(lcnt[l], 64)) {
      int p = lbase[l] + k;
      int fb = b * 32 + l;
      if (p < Q2CAP) q2[(size_t)(fb * 16 + sub2) * Q2CAP + p] = lst[l][k];
    }
  }
}

// P3: assemble 196-node CSR window in LDS, write dense+coalesced; fused premul.
__global__ __launch_bounds__(256) void p3_k(const unsigned* __restrict__ q2,
                                            const int* __restrict__ qc2,
                                            const float* __restrict__ x,
                                            int* __restrict__ cursor,
                                            int* __restrict__ csr,
                                            unsigned* __restrict__ xs) {
  __shared__ int lcsr[SBN * CAP];   // 37632 B
  __shared__ int lcnt[SBN];
  int tid = threadIdx.x;
  int fb = blockIdx.x;              // 0..511
  int b = fb >> 5, sb = fb & 31;
  int node_lo = b * B1 + sb * SBN;
  int node_hi = min(node_lo + SBN, (b + 1) * B1);
  int nn = node_hi - node_lo;       // 196 or 174 (sb=31)
  if (nn <= 0) return;
  for (int i = tid; i < SBN; i += 256) lcnt[i] = 0;
  __syncthreads();
  int base_off = sb * SBN;
#pragma unroll 1
  for (int s2 = 0; s2 < 16; ++s2) {
    int qi = fb * 16 + s2;
    int len = min(qc2[qi * 16], Q2CAP);
    for (int i = tid; i < len; i += 256) {
      unsigned p = q2[(size_t)qi * Q2CAP + i];
      int local = (int)(p & 8191u) - base_off;   // 0..nn-1 by construction
      int s = (int)(p >> 13);
      int pos = atomicAdd(&lcnt[local], 1);
      if (pos < CAP) lcsr[local * CAP + pos] = s;
    }
  }
  __syncthreads();
  for (int i = tid; i < nn; i += 256) cursor[node_lo + i] = lcnt[i];
  // dense contiguous CSR write: nn*CAP ints = nn*12 uint4, 16B aligned
  uint4* gout = (uint4*)&csr[(size_t)node_lo * CAP];
  const uint4* lin = (const uint4*)lcsr;
  for (int i = tid; i < nn * (CAP / 4); i += 256) gout[i] = lin[i];
  // fused premul: xs[node] = x[node] * rsqrt(deg+1), packed bf16
  for (int i = tid; i < nn * 32; i += 256) {
    int ln = i >> 5, j = i & 31;
    int node = node_lo + ln;
    float dsc = rsqrtf((float)lcnt[ln] + 1.0f);
    float2 v = ((const float2*)x)[(size_t)node * 32 + j];
    xs[(size_t)node * 32 + j] = pack_bf16(v.x * dsc, v.y * dsc);
  }
}

// ---------------- merged setup: weights, BN fold, boundaries, zeroing ----------------

__global__ __launch_bounds__(256) void setup_k(
    const float* __restrict__ W0, const float* __restrict__ W1,
    const float* __restrict__ W2, unsigned short* __restrict__ wt0,
    unsigned short* __restrict__ wt1, unsigned short* __restrict__ wt2,
    const float* __restrict__ b0, const float* __restrict__ g0,
    const float* __restrict__ be0, const float* __restrict__ m0,
    const float* __restrict__ v0, const float* __restrict__ b1,
    const float* __restrict__ g1, const float* __restrict__ be1,
    const float* __restrict__ m1, const float* __restrict__ v1,
    float* __restrict__ s0, float* __restrict__ h0,
    float* __restrict__ s1, float* __restrict__ h1,
    const int* __restrict__ batch, int* __restrict__ start,
    int* __restrict__ zbase) {
  int bid = blockIdx.x;
  if (bid < 128) {                       // weight prep
    int i = bid * 256 + threadIdx.x;
    if (i < 8192) {                      // Wt0 [128][64]
      int d = i >> 6, k = i & 63;
      wt0[d * 64 + k] = bf16_1(W0[k * 128 + d]);
    } else if (i < 24576) {              // Wt1 [128][128]
      int j = i - 8192;
      int d = j >> 7, k = j & 127;
      wt1[d * 128 + k] = bf16_1(W1[k * 128 + d]);
    } else if (i < 32768) {              // Wt2 [64][128]
      int j = i - 24576;
      int d = j >> 7, k = j & 127;
      wt2[d * 128 + k] = bf16_1(W2[k * 64 + d]);
    }
  } else if (bid == 128) {               // BN fold
    int i = threadIdx.x;
    if (i < 128) {
      float s = g0[i] * rsqrtf(v0[i] + EPSF);
      s0[i] = s;
      h0[i] = be0[i] + (b0[i] - m0[i]) * s;
    } else {
      int j = i - 128;
      float s = g1[j] * rsqrtf(v1[j] + EPSF);
      s1[j] = s;
      h1[j] = be1[j] + (b1[j] - m1[j]) * s;
    }
  } else if (bid < 129 + NB) {           // graph boundaries
    int i = (bid - 129) * 256 + threadIdx.x;
    if (i >= NN) return;
    int b = batch[i];
    if (i == 0) {
      for (int g = 0; g <= b; ++g) start[g] = 0;
    } else {
      int p = batch[i - 1];
      for (int g = p + 1; g <= b; ++g) start[g] = i;
    }
    if (i == NN - 1) {
      for (int g = b + 1; g <= GG; ++g) start[g] = NN;
    }
  } else {                               // zero pacc/qc1/qc2/done
    int i = (bid - 129 - NB) * 256 + threadIdx.x;
    if (i < ZWORDS) zbase[i] = 0;
  }
}

// ---------------- Aggregation (bf16 in, fp32 accumulate, bf16 out) ----------------
// out[n] = dinv[n] * ( sum_{s} xp[s] + xp[n] ), xp premultiplied by dinv[s].
// One coalesced index load per node; self appended as pseudo-neighbor.
// Loops have WAVE-UNIFORM trip counts; __shfl always full-wave. Only gathers
// predicated (R8 lesson: ds_bpermute from EXEC-inactive lane is undefined).

// 64-ch: row = 128B = 8 lanes x uint4; 16 edges per iteration (2 in flight).
__global__ __launch_bounds__(256) void aggp64_k(const unsigned* __restrict__ xp,
                                                const int* __restrict__ counts,
                                                const int* __restrict__ csr,
                                                uint4* __restrict__ out4) {
  int node = blockIdx.x * 4 + (threadIdx.x >> 6);
  if (node >= NN) return;
  int lane = threadIdx.x & 63;
  int g = lane >> 3, sl = lane & 7;
  int raw = counts[node];
  float di = rsqrtf((float)raw + 1.0f);
  int cnt = min(raw, CAP);
  int idx = (lane < cnt) ? csr[node * CAP + lane] : node;  // self at pos cnt
  cnt += 1;
  unsigned slb = (unsigned)(sl << 4);
  float a[8] = {0.f, 0.f, 0.f, 0.f, 0.f, 0.f, 0.f, 0.f};
  for (int base = 0; base < cnt; base += 16) {   // uniform trip count
    int j0 = base + g, j1 = base + g + 8;
    int s0 = __shfl(idx, j0, 64);                // j <= 63 always
    int s1 = __shfl(idx, j1, 64);
    if (j0 < cnt) acc_u4(a, ldg_off(xp, (unsigned)s0 * 128u + slb));
    if (j1 < cnt) acc_u4(a, ldg_off(xp, (unsigned)s1 * 128u + slb));
  }
#pragma unroll
  for (int i = 0; i < 8; ++i) {
    a[i] += __shfl_xor(a[i], 8, 64);
    a[i] += __shfl_xor(a[i], 16, 64);
    a[i] += __shfl_xor(a[i], 32, 64);
  }
  if (g == 0) {
    uint4 o;
    o.x = pack_bf16(a[0] * di, a[1] * di);
    o.y = pack_bf16(a[2] * di, a[3] * di);
    o.z = pack_bf16(a[4] * di, a[5] * di);
    o.w = pack_bf16(a[6] * di, a[7] * di);
    out4[(size_t)node * 8 + sl] = o;
  }
}

// 128-ch: row = 256B = 16 lanes x uint4; 16 edges per iteration (4 in flight).
__global__ __launch_bounds__(256) void aggp128_k(const unsigned* __restrict__ xp,
                                                 const int* __restrict__ counts,
                                                 const int* __restrict__ csr,
                                                 uint4* __restrict__ out4) {
  int node = blockIdx.x * 4 + (threadIdx.x >> 6);
  if (node >= NN) return;
  int lane = threadIdx.x & 63;
  int q = lane >> 4, sl = lane & 15;
  int raw = counts[node];
  float di = rsqrtf((float)raw + 1.0f);
  int cnt = min(raw, CAP);
  int idx = (lane < cnt) ? csr[node * CAP + lane] : node;  // self at pos cnt
  cnt += 1;
  unsigned slb = (unsigned)(sl << 4);
  float a[8] = {0.f, 0.f, 0.f, 0.f, 0.f, 0.f, 0.f, 0.f};
  for (int base = 0; base < cnt; base += 16) {   // uniform trip count
    int j0 = base + q, j1 = base + q + 4, j2 = base + q + 8, j3 = base + q + 12;
    int s0 = __shfl(idx, j0, 64);                // j <= 63 always
    int s1 = __shfl(idx, j1, 64);
    int s2 = __shfl(idx, j2, 64);
    int s3 = __shfl(idx, j3, 64);
    if (j0 < cnt) acc_u4(a, ldg_off(xp, (unsigned)s0 * 256u + slb));
    if (j1 < cnt) acc_u4(a, ldg_off(xp, (unsigned)s1 * 256u + slb));
    if (j2 < cnt) acc_u4(a, ldg_off(xp, (unsigned)s2 * 256u + slb));
    if (j3 < cnt) acc_u4(a, ldg_off(xp, (unsigned)s3 * 256u + slb));
  }
#pragma unroll
  for (int i = 0; i < 8; ++i) {
    a[i] += __shfl_xor(a[i], 16, 64);
    a[i] += __shfl_xor(a[i], 32, 64);
  }
  if (q == 0) {
    uint4 o;
    o.x = pack_bf16(a[0] * di, a[1] * di);
    o.y = pack_bf16(a[2] * di, a[3] * di);
    o.z = pack_bf16(a[4] * di, a[5] * di);
    o.w = pack_bf16(a[6] * di, a[7] * di);
    out4[(size_t)node * 16 + sl] = o;
  }
}

// final agg + bias + LayerNorm (64-ch bf16 in, fp32 out), eighth-wave gather.
__global__ __launch_bounds__(256) void agg_ln_k(const unsigned* __restrict__ xp,
                                                const int* __restrict__ counts,
                                                const int* __restrict__ csr,
                                                const float* __restrict__ bias,
                                                const float* __restrict__ lng,
                                                const float* __restrict__ lnb,
                                                float* __restrict__ out) {
  int node = blockIdx.x * 4 + (threadIdx.x >> 6);
  if (node >= NN) return;
  int lane = threadIdx.x & 63;
  int g = lane >> 3, sl = lane & 7;
  int raw = counts[node];
  float di = rsqrtf((float)raw + 1.0f);
  int cnt = min(raw, CAP);
  int idx = (lane < cnt) ? csr[node * CAP + lane] : node;  // self at pos cnt
  cnt += 1;
  unsigned slb = (unsigned)(sl << 4);
  float a[8] = {0.f, 0.f, 0.f, 0.f, 0.f, 0.f, 0.f, 0.f};
  for (int base = 0; base < cnt; base += 16) {   // uniform trip count
    int j0 = base + g, j1 = base + g + 8;
    int s0 = __shfl(idx, j0, 64);                // j <= 63 always
    int s1 = __shfl(idx, j1, 64);
    if (j0 < cnt) acc_u4(a, ldg_off(xp, (unsigned)s0 * 128u + slb));
    if (j1 < cnt) acc_u4(a, ldg_off(xp, (unsigned)s1 * 128u + slb));
  }
#pragma unroll
  for (int i = 0; i < 8; ++i) {
    a[i] += __shfl_xor(a[i], 8, 64);
    a[i] += __shfl_xor(a[i], 16, 64);
    a[i] += __shfl_xor(a[i], 32, 64);
  }
  // all lanes now hold channels sl*8..sl*8+7
  float4 b0 = ((const float4*)bias)[sl * 2];
  float4 b1 = ((const float4*)bias)[sl * 2 + 1];
  float v[8];
  v[0] = a[0] * di + b0.x; v[1] = a[1] * di + b0.y;
  v[2] = a[2] * di + b0.z; v[3] = a[3] * di + b0.w;
  v[4] = a[4] * di + b1.x; v[5] = a[5] * di + b1.y;
  v[6] = a[6] * di + b1.z; v[7] = a[7] * di + b1.w;
  float s = ((v[0] + v[1]) + (v[2] + v[3])) + ((v[4] + v[5]) + (v[6] + v[7]));
#pragma unroll
  for (int off = 1; off < 8; off <<= 1) s += __shfl_xor(s, off, 64);
  float mu = s * (1.f / 64.f);
  float vs = 0.f;
#pragma unroll
  for (int i = 0; i < 8; ++i) {
    v[i] -= mu;
    vs += v[i] * v[i];
  }
#pragma unroll
  for (int off = 1; off < 8; off <<= 1) vs += __shfl_xor(vs, off, 64);
  float r = rsqrtf(vs * (1.f / 64.f) + EPSF);
  if (g == 0) {
    float4 g0 = ((const float4*)lng)[sl * 2];
    float4 g1 = ((const float4*)lng)[sl * 2 + 1];
    float4 e0 = ((const float4*)lnb)[sl * 2];
    float4 e1 = ((const float4*)lnb)[sl * 2 + 1];
    float4 o0, o1;
    o0.x = v[0] * r * g0.x + e0.x; o0.y = v[1] * r * g0.y + e0.y;
    o0.z = v[2] * r * g0.z + e0.z; o0.w = v[3] * r * g0.w + e0.w;
    o1.x = v[4] * r * g1.x + e1.x; o1.y = v[5] * r * g1.y + e1.y;
    o1.z = v[6] * r * g1.z + e1.z; o1.w = v[7] * r * g1.w + e1.w;
    ((float4*)out)[(size_t)node * 16 + sl * 2] = o0;
    ((float4*)out)[(size_t)node * 16 + sl * 2 + 1] = o1;
  }
}

// ---------------- MFMA GEMM: C[N,D] = A[N,K] @ W[K,D], bf16 in/out ----------------

#define EPI_BNRELU 1
#define EPI_BNRELU_PREMUL 2
#define EPI_PREMUL 3

template <int K, int D, int EPI>
__global__ __launch_bounds__(256, 2) void gemm_mfma_k(
    const unsigned short* __restrict__ Abf,   // [N][K] bf16
    const unsigned short* __restrict__ Wt,    // [D][K] bf16 (pre-transposed)
    const float* __restrict__ scale,          // [D]
    const float* __restrict__ shift,          // [D]
    const int* __restrict__ counts,
    unsigned short* __restrict__ C) {         // [N][D] bf16
  constexpr int BM = 64;
  constexpr int LK = K + 8;                   // +16B pad: 2-way bank alias (free)
  constexpr int NT = D / 16;
  __shared__ unsigned short sA[BM * LK];
  __shared__ unsigned short sW[D * LK];
  int tid = threadIdx.x;
  int row0 = blockIdx.x * BM;
  for (int i = tid; i < BM * K / 8; i += 256) {
    int r = i / (K / 8), c8 = i % (K / 8);
    int gr = row0 + r;
    short8 v = {};
    if (gr < NN) v = *(const short8*)&Abf[(size_t)gr * K + c8 * 8];
    *(short8*)&sA[r * LK + c8 * 8] = v;
  }
  for (int i = tid; i < D * K / 8; i += 256) {
    int d = i / (K / 8), c8 = i % (K / 8);
    *(short8*)&sW[d * LK + c8 * 8] = *(const short8*)&Wt[d * K + c8 * 8];
  }
  __syncthreads();
  int wid = tid >> 6, lane = tid & 63;
  int lr = lane & 15, kg = lane >> 4;
  f32x4 acc[NT];
#pragma unroll
  for (int t = 0; t < NT; ++t) acc[t] = (f32x4){0.f, 0.f, 0.f, 0.f};
  const unsigned short* pa = &sA[(wid * 16 + lr) * LK + kg * 8];
#pragma unroll
  for (int kk = 0; kk < K / 32; ++kk) {
    short8 a = *(const short8*)(pa + kk * 32);
#pragma unroll
    for (int t = 0; t < NT; ++t) {
      short8 b = *(const short8*)&sW[(t * 16 + lr) * LK + kk * 32 + kg * 8];
      acc[t] = __builtin_amdgcn_mfma_f32_16x16x32_bf16(a, b, acc[t], 0, 0, 0);
    }
  }
  int rbase = row0 + wid * 16 + kg * 4;
  float dv[4];
  if (EPI != EPI_BNRELU) {
#pragma unroll
    for (int j = 0; j < 4; ++j)
      dv[j] = (rbase + j < NN) ? rsqrtf((float)counts[rbase + j] + 1.0f) : 0.f;
  }
#pragma unroll
  for (int t = 0; t < NT; ++t) {
    int col = t * 16 + lr;
    float sc = 1.f, sh = 0.f;
    if (EPI != EPI_PREMUL) { sc = scale[col]; sh = shift[col]; }
#pragma unroll
    for (int j = 0; j < 4; ++j) {
      int r = rbase + j;
      if (r >= NN) continue;
      float v = acc[t][j];
      if (EPI != EPI_PREMUL) v = fmaxf(v * sc + sh, 0.f);
      if (EPI != EPI_BNRELU) v *= dv[j];
      C[(size_t)r * D + col] = bf16_1(v);
    }
  }
}

// ---------------- Pooling (two-stage; no device fences) ----------------

__global__ __launch_bounds__(256) void pool1_k(const float* __restrict__ ne,
                                               const int* __restrict__ batch,
                                               float* __restrict__ acc) {
  const int CHUNK = (NN + PB - 1) / PB;  // 98
  int i0 = blockIdx.x * CHUNK;
  int i1 = min(i0 + CHUNK, NN);
  if (i0 >= NN) return;
  int c = threadIdx.x & 63;
  int part = threadIdx.x >> 6;  // 0..3
  int cur = -1;
  float a = 0.f;
  for (int i = i0 + part; i < i1; i += 4) {
    int b = batch[i];  // wave-uniform
    if (b != cur) {
      if (cur >= 0) atomicAdd(&acc[cur * 64 + c], a);
      cur = b;
      a = 0.f;
    }
    a += ne[(size_t)i * 64 + c];
  }
  if (cur >= 0) atomicAdd(&acc[cur * 64 + c], a);
}

__global__ __launch_bounds__(256) void pool2_k(const float* __restrict__ acc,
                                               const int* __restrict__ start,
                                               float* __restrict__ ge) {
  int i = blockIdx.x * 256 + threadIdx.x;
  if (i >= GG * 64) return;
  int g = i >> 6;
  float cnt = (float)(start[g + 1] - start[g]);
  ge[i] = acc[i] / fmaxf(cnt, 1.f);
}

// ---------------- launch ----------------

extern "C" void kernel_launch(void* const* d_in, const int* in_sizes, int n_in,
                              void* d_out, int out_size, void* d_ws, size_t ws_size,
                              hipStream_t stream) {
  const float* x = (const float*)d_in[0];
  const int* ei = (const int*)d_in[1];
  const int* srcv = ei;
  const int* dstv = ei + EE;
  const int* batch = (const int*)d_in[2];
  const float* W0 = (const float*)d_in[3];
  const float* b0 = (const float*)d_in[4];
  const float* W1 = (const float*)d_in[5];
  const float* b1 = (const float*)d_in[6];
  const float* W2 = (const float*)d_in[7];
  const float* b2 = (const float*)d_in[8];
  const float* bn0g = (const float*)d_in[9];
  const float* bn0b = (const float*)d_in[10];
  const float* bn0m = (const float*)d_in[11];
  const float* bn0v = (const float*)d_in[12];
  const float* bn1g = (const float*)d_in[13];
  const float* bn1b = (const float*)d_in[14];
  const float* bn1m = (const float*)d_in[15];
  const float* bn1v = (const float*)d_in[16];
  const float* lng = (const float*)d_in[17];
  const float* lnb = (const float*)d_in[18];

  float* out_nodes = (float*)d_out;
  float* out_graph = out_nodes + (size_t)NN * 64;

  char* ws = (char*)d_ws;
  size_t off = 0;
  auto carve = [&](size_t bytes) {
    void* p = ws + off;
    off = (off + bytes + 255) & ~(size_t)255;
    return p;
  };
  int* cursor = (int*)carve((size_t)NN * 4);              // raw degree counts
  float* pacc = (float*)carve((size_t)GG * 64 * 4);       // 16384 } zeroed by
  int* qc1 = (int*)carve(16 * 64 * 16 * 4);               // 65536 } setup_k
  int* qc2 = (int*)carve(512 * 16 * 16 * 4);              // 524288} (ZWORDS
  int* done = (int*)carve(256);                           // 256   }  words)
  int* gstart = (int*)carve((size_t)(GG + 1) * 4);
  unsigned short* wt0 = (unsigned short*)carve(8192 * 2);
  unsigned short* wt1 = (unsigned short*)carve(16384 * 2);
  unsigned short* wt2 = (unsigned short*)carve(8192 * 2);
  float* s0 = (float*)carve(128 * 4);
  float* h0 = (float*)carve(128 * 4);
  float* s1 = (float*)carve(128 * 4);
  float* h1 = (float*)carve(128 * 4);
  int* csr = (int*)carve((size_t)NN * CAP * 4);           // 19.2 MB
  char* bufA = (char*)carve((size_t)NN * 128 * 4);        // 51.2 MB
  char* bufB = (char*)carve((size_t)NN * 128 * 4);        // 51.2 MB

  // buffer life plan (aliases; each region dead before its successor writes):
  unsigned* q1 = (unsigned*)bufB;            // 8.4 MB,  dead after p2
  unsigned* q2 = (unsigned*)bufA;            // 16.8 MB, dead after p3
  unsigned* xs = (unsigned*)(bufA + (size_t)32 * 1024 * 1024);  // 12.8 MB, by p3
  void* a0 = bufB;                           // aggp64 out (q1 dead)
  void* h0p = bufA;                          // gemm0 out (q2 dead; xs@32MB clear)
  void* a1 = bufB;                           // aggp128 out (a0 dead)
  void* h1b = bufA;                          // gemm1 out (h0p dead)
  void* xw2p = bufB;                         // gemm2 out (a1 dead)

  setup_k<<<129 + NB + ZB, 256, 0, stream>>>(W0, W1, W2, wt0, wt1, wt2,
                                             b0, bn0g, bn0b, bn0m, bn0v,
                                             b1, bn1g, bn1b, bn1m, bn1v,
                                             s0, h0, s1, h1, batch, gstart,
                                             (int*)pacc);
  // 3-pass LDS-assembled CSR build (no scattered global stores) + fused premul
  p1_k<<<EG, 256, 0, stream>>>(srcv, dstv, qc1, q1);
  p2_k<<<16 * 256, 256, 0, stream>>>(q1, qc1, qc2, q2);
  p3_k<<<512, 256, 0, stream>>>(q2, qc2, x, cursor, csr, xs);

  int agrid = (NN + 3) / 4;    // 25000
  int mgrid = (NN + 63) / 64;  // 1563

  // a0 = agg(xs) (bf16, 64ch)
  aggp64_k<<<agrid, 256, 0, stream>>>(xs, cursor, csr, (uint4*)a0);
  // h0p = relu(bn(a0@W0)) * dinv (bf16, 128ch)
  gemm_mfma_k<64, 128, EPI_BNRELU_PREMUL><<<mgrid, 256, 0, stream>>>(
      (const unsigned short*)a0, wt0, s0, h0, cursor, (unsigned short*)h0p);
  // a1 = agg(h0p) (bf16, 128ch)
  aggp128_k<<<agrid, 256, 0, stream>>>((const unsigned*)h0p, cursor, csr,
                                       (uint4*)a1);
  // h1 = relu(bn(a1@W1)) (bf16, 128ch)
  gemm_mfma_k<128, 128, EPI_BNRELU><<<mgrid, 256, 0, stream>>>(
      (const unsigned short*)a1, wt1, s1, h1, cursor, (unsigned short*)h1b);
  // xw2p = (h1@W2) * dinv (bf16, 64ch; bias b2 post-agg)
  gemm_mfma_k<128, 64, EPI_PREMUL><<<mgrid, 256, 0, stream>>>(
      (const unsigned short*)h1b, wt2, s1, h1, cursor, (unsigned short*)xw2p);
  // out_nodes = LN(agg(xw2p) + b2)
  agg_ln_k<<<agrid, 256, 0, stream>>>((const unsigned*)xw2p, cursor, csr, b2,
                                      lng, lnb, out_nodes);
  // two-stage graph mean pool (no device-scope fences)
  pool1_k<<<PB, 256, 0, stream>>>(out_nodes, batch, pacc);
  pool2_k<<<(GG * 64 + 255) / 256, 256, 0, stream>>>(pacc, gstart, out_graph);
}